// Round 1
// baseline (1086.210 us; speedup 1.0000x reference)
//
#include <hip/hip_runtime.h>
#include <cstdint>
#include <cstddef>

#define ROW 963  // 3 coords + 64 + 128 + 256 + 512

// NCHW [B,C,S,S] -> NHWC [B,S,S,C]
__global__ __launch_bounds__(256) void transpose_k(const float* __restrict__ in,
                                                   float* __restrict__ out,
                                                   int C, int S) {
    int b = blockIdx.y;
    int idx = blockIdx.x * 256 + threadIdx.x;
    int SS = S * S;
    int total = C * SS;
    if (idx >= total) return;
    int c = idx / SS;
    int sp = idx - c * SS;
    out[((size_t)b * SS + sp) * C + c] = in[(size_t)b * total + idx];
}

template <bool NHWC>
__global__ __launch_bounds__(256) void proj_k(
    const float* __restrict__ coord,  // [N,3] (batch 0 coords, shared)
    const float* __restrict__ f1, const float* __restrict__ f2,
    const float* __restrict__ f3, const float* __restrict__ f4,
    float* __restrict__ out, int N) {
    int n = blockIdx.x;
    int b = blockIdx.y;

    float X = coord[3 * n + 0];
    float Y = coord[3 * n + 1];
    float Z = coord[3 * n + 2];

    // h = clip(250*(-Y)/(-Z) + 112, 0, 223); w = clip(250*X/(-Z) + 112, 0, 223)
    float h = fminf(fmaxf((250.0f * -Y) / (-Z) + 112.0f, 0.0f), 223.0f);
    float w = fminf(fmaxf((250.0f * X) / (-Z) + 112.0f, 0.0f), 223.0f);

    size_t orow = ((size_t)b * N + n) * ROW;

    if (threadIdx.x < 3) {
        out[orow + threadIdx.x] = coord[3 * n + threadIdx.x];
    }

    for (int c = threadIdx.x; c < 960; c += 256) {
        const float* T;
        int S, C, cc;
        // boundaries 64/192/448 are multiples of 64 -> wave-uniform branch
        if (c < 64) {
            T = f1; S = 56; C = 64;  cc = c;
        } else if (c < 192) {
            T = f2; S = 28; C = 128; cc = c - 64;
        } else if (c < 448) {
            T = f3; S = 14; C = 256; cc = c - 192;
        } else {
            T = f4; S = 7;  C = 512; cc = c - 448;
        }
        // 224/S is an exact power of two for S in {56,28,14,7}
        float scale = (float)S * (1.0f / 224.0f);
        float sm1 = (float)(S - 1);
        float x = fminf(fmaxf(h * scale, 0.0f), sm1);
        float y = fminf(fmaxf(w * scale, 0.0f), sm1);

        float x1f = floorf(x), x2f = ceilf(x);
        float y1f = floorf(y), y2f = ceilf(y);
        int x1 = (int)x1f, x2 = (int)x2f;
        int y1 = (int)y1f, y2 = (int)y2f;

        float Q11, Q12, Q21, Q22;
        if (NHWC) {
            const float* base = T + ((size_t)b * S * S) * C + cc;
            Q11 = base[(size_t)(x1 * S + y1) * C];
            Q12 = base[(size_t)(x1 * S + y2) * C];
            Q21 = base[(size_t)(x2 * S + y1) * C];
            Q22 = base[(size_t)(x2 * S + y2) * C];
        } else {
            const float* base = T + ((size_t)b * C + cc) * (size_t)(S * S);
            Q11 = base[x1 * S + y1];
            Q12 = base[x1 * S + y2];
            Q21 = base[x2 * S + y1];
            Q22 = base[x2 * S + y2];
        }

        float dx1 = x - x1f, dx2 = x2f - x;
        float dy1 = y - y1f, dy2 = y2f - y;
        // matches: w11*Q11 + w21*Q21 + w12*Q12 + w22*Q22
        float v = (dx2 * dy2) * Q11 + (dx1 * dy2) * Q21 +
                  (dx2 * dy1) * Q12 + (dx1 * dy1) * Q22;
        out[orow + 3 + c] = v;
    }
}

extern "C" void kernel_launch(void* const* d_in, const int* in_sizes, int n_in,
                              void* d_out, int out_size, void* d_ws, size_t ws_size,
                              hipStream_t stream) {
    const float* inputs = (const float*)d_in[0];  // [B,N,3]; batch 0 used as coords
    const float* f1 = (const float*)d_in[1];      // [B,64,56,56]
    const float* f2 = (const float*)d_in[2];      // [B,128,28,28]
    const float* f3 = (const float*)d_in[3];      // [B,256,14,14]
    const float* f4 = (const float*)d_in[4];      // [B,512,7,7]
    float* out = (float*)d_out;

    int B = in_sizes[1] / (64 * 56 * 56);
    int N = in_sizes[0] / (B * 3);

    size_t n1 = (size_t)B * 56 * 56 * 64;
    size_t n2 = (size_t)B * 28 * 28 * 128;
    size_t n3 = (size_t)B * 14 * 14 * 256;
    size_t n4 = (size_t)B * 7 * 7 * 512;
    size_t need = (n1 + n2 + n3 + n4) * sizeof(float);

    dim3 blk(256);
    if (ws_size >= need) {
        float* t1 = (float*)d_ws;
        float* t2 = t1 + n1;
        float* t3 = t2 + n2;
        float* t4 = t3 + n3;
        transpose_k<<<dim3((64 * 56 * 56 + 255) / 256, B), blk, 0, stream>>>(f1, t1, 64, 56);
        transpose_k<<<dim3((128 * 28 * 28 + 255) / 256, B), blk, 0, stream>>>(f2, t2, 128, 28);
        transpose_k<<<dim3((256 * 14 * 14 + 255) / 256, B), blk, 0, stream>>>(f3, t3, 256, 14);
        transpose_k<<<dim3((512 * 7 * 7 + 255) / 256, B), blk, 0, stream>>>(f4, t4, 512, 7);
        proj_k<true><<<dim3(N, B), blk, 0, stream>>>(inputs, t1, t2, t3, t4, out, N);
    } else {
        proj_k<false><<<dim3(N, B), blk, 0, stream>>>(inputs, f1, f2, f3, f4, out, N);
    }
}

// Round 2
// 860.822 us; speedup vs baseline: 1.2618x; 1.2618x over previous
//
#include <hip/hip_runtime.h>
#include <cstdint>
#include <cstddef>

#define ROW 963  // 3 coords + 64 + 128 + 256 + 512 channels

__device__ __forceinline__ float bf2f(unsigned short u) {
    return __uint_as_float(((unsigned int)u) << 16);
}
__device__ __forceinline__ unsigned short f2bf(float v) {
    unsigned int u = __float_as_uint(v);
    // round-to-nearest-even
    u += 0x7FFFu + ((u >> 16) & 1u);
    return (unsigned short)(u >> 16);
}

// Fused NCHW fp32 -> NHWC bf16 for all 4 pyramid levels.
// Per-batch element counts: f1 64*56*56=200704, f2 128*28*28=100352,
// f3 256*14*14=50176, f4 512*7*7=25088. Cumulative: 200704/301056/351232/376320
// -- all multiples of 64, so the level branch is wave-uniform.
__global__ __launch_bounds__(256) void trans_all_k(
    const float* __restrict__ f1, const float* __restrict__ f2,
    const float* __restrict__ f3, const float* __restrict__ f4,
    unsigned short* __restrict__ o1, unsigned short* __restrict__ o2,
    unsigned short* __restrict__ o3, unsigned short* __restrict__ o4) {
    int r = blockIdx.x * 256 + threadIdx.x;
    int b = blockIdx.y;
    const float* src; unsigned short* dst; int C, SS, rr, c, sp;
    if (r < 200704)      { src = f1; dst = o1; C = 64;  SS = 3136; rr = r;
                           c = rr / 3136; sp = rr - c * 3136; }
    else if (r < 301056) { src = f2; dst = o2; C = 128; SS = 784;  rr = r - 200704;
                           c = rr / 784;  sp = rr - c * 784; }
    else if (r < 351232) { src = f3; dst = o3; C = 256; SS = 196;  rr = r - 301056;
                           c = rr / 196;  sp = rr - c * 196; }
    else if (r < 376320) { src = f4; dst = o4; C = 512; SS = 49;   rr = r - 351232;
                           c = rr / 49;   sp = rr - c * 49; }
    else return;
    float v = src[(size_t)b * C * SS + rr];                 // coalesced read
    dst[((size_t)b * SS + sp) * C + c] = f2bf(v);           // strided write, L2-resident
}

// One block per (point n, batch b). Thread t<240 owns channels [4t,4t+4):
// chunk-level boundaries 16/48/112 (within-wave select of per-level params).
// Per-level geometry computed ONCE per thread, inner work = 4x ushort4 loads
// + 16 FMAs. Row staged in LDS, then stored fully coalesced.
__global__ __launch_bounds__(256) void proj_bf16_k(
    const float* __restrict__ coord,  // [N,3], batch-0 coords shared across b
    const unsigned short* __restrict__ t1, const unsigned short* __restrict__ t2,
    const unsigned short* __restrict__ t3, const unsigned short* __restrict__ t4,
    float* __restrict__ out, int N) {
    int n = blockIdx.x;
    int b = blockIdx.y;
    int t = threadIdx.x;

    __shared__ float row[ROW + 1];

    float X = coord[3 * n + 0];
    float Y = coord[3 * n + 1];
    float Z = coord[3 * n + 2];
    // exact same fp32 op sequence as the reference (round-1 absmax was 0.0)
    float h = fminf(fmaxf((250.0f * -Y) / (-Z) + 112.0f, 0.0f), 223.0f);
    float w = fminf(fmaxf((250.0f * X) / (-Z) + 112.0f, 0.0f), 223.0f);

    if (t < 3) row[t] = coord[3 * n + t];

    if (t < 240) {
        const unsigned short* T; int S, C, cs;
        if (t < 16)       { T = t1; S = 56; C = 64;  cs = 0; }
        else if (t < 48)  { T = t2; S = 28; C = 128; cs = 16; }
        else if (t < 112) { T = t3; S = 14; C = 256; cs = 48; }
        else              { T = t4; S = 7;  C = 512; cs = 112; }
        int cc = (t - cs) * 4;  // channel within level, multiple of 4 -> 8B aligned

        float scale = (float)S * (1.0f / 224.0f);  // exact power-of-two mul
        float sm1 = (float)(S - 1);
        float x = fminf(fmaxf(h * scale, 0.0f), sm1);
        float y = fminf(fmaxf(w * scale, 0.0f), sm1);
        float x1f = floorf(x), x2f = ceilf(x);
        float y1f = floorf(y), y2f = ceilf(y);
        int x1 = (int)x1f, x2 = (int)x2f;
        int y1 = (int)y1f, y2 = (int)y2f;

        const unsigned short* base = T + (size_t)b * (S * S) * C + cc;
        const ushort4* p11 = (const ushort4*)(base + (size_t)(x1 * S + y1) * C);
        const ushort4* p12 = (const ushort4*)(base + (size_t)(x1 * S + y2) * C);
        const ushort4* p21 = (const ushort4*)(base + (size_t)(x2 * S + y1) * C);
        const ushort4* p22 = (const ushort4*)(base + (size_t)(x2 * S + y2) * C);
        ushort4 q11 = *p11, q12 = *p12, q21 = *p21, q22 = *p22;

        float dx1 = x - x1f, dx2 = x2f - x;
        float dy1 = y - y1f, dy2 = y2f - y;
        float w11 = dx2 * dy2, w21 = dx1 * dy2, w12 = dx2 * dy1, w22 = dx1 * dy1;

        float v0 = w11 * bf2f(q11.x) + w21 * bf2f(q21.x) + w12 * bf2f(q12.x) + w22 * bf2f(q22.x);
        float v1 = w11 * bf2f(q11.y) + w21 * bf2f(q21.y) + w12 * bf2f(q12.y) + w22 * bf2f(q22.y);
        float v2 = w11 * bf2f(q11.z) + w21 * bf2f(q21.z) + w12 * bf2f(q12.z) + w22 * bf2f(q22.z);
        float v3 = w11 * bf2f(q11.w) + w21 * bf2f(q21.w) + w12 * bf2f(q12.w) + w22 * bf2f(q22.w);

        int o = 3 + 4 * t;
        row[o + 0] = v0; row[o + 1] = v1; row[o + 2] = v2; row[o + 3] = v3;
    }
    __syncthreads();

    size_t orow = ((size_t)b * N + n) * ROW;
    #pragma unroll
    for (int i = t; i < ROW; i += 256) out[orow + i] = row[i];
}

// Fallback: direct NCHW fp32 gather (only if d_ws is too small -- not expected).
__global__ __launch_bounds__(256) void proj_nchw_k(
    const float* __restrict__ coord,
    const float* __restrict__ f1, const float* __restrict__ f2,
    const float* __restrict__ f3, const float* __restrict__ f4,
    float* __restrict__ out, int N) {
    int n = blockIdx.x, b = blockIdx.y;
    float X = coord[3 * n + 0], Y = coord[3 * n + 1], Z = coord[3 * n + 2];
    float h = fminf(fmaxf((250.0f * -Y) / (-Z) + 112.0f, 0.0f), 223.0f);
    float w = fminf(fmaxf((250.0f * X) / (-Z) + 112.0f, 0.0f), 223.0f);
    size_t orow = ((size_t)b * N + n) * ROW;
    if (threadIdx.x < 3) out[orow + threadIdx.x] = coord[3 * n + threadIdx.x];
    for (int c = threadIdx.x; c < 960; c += 256) {
        const float* T; int S, C, cc;
        if (c < 64)       { T = f1; S = 56; C = 64;  cc = c; }
        else if (c < 192) { T = f2; S = 28; C = 128; cc = c - 64; }
        else if (c < 448) { T = f3; S = 14; C = 256; cc = c - 192; }
        else              { T = f4; S = 7;  C = 512; cc = c - 448; }
        float scale = (float)S * (1.0f / 224.0f);
        float sm1 = (float)(S - 1);
        float x = fminf(fmaxf(h * scale, 0.0f), sm1);
        float y = fminf(fmaxf(w * scale, 0.0f), sm1);
        float x1f = floorf(x), x2f = ceilf(x);
        float y1f = floorf(y), y2f = ceilf(y);
        int x1 = (int)x1f, x2 = (int)x2f, y1 = (int)y1f, y2 = (int)y2f;
        const float* base = T + ((size_t)b * C + cc) * (size_t)(S * S);
        float Q11 = base[x1 * S + y1], Q12 = base[x1 * S + y2];
        float Q21 = base[x2 * S + y1], Q22 = base[x2 * S + y2];
        float dx1 = x - x1f, dx2 = x2f - x, dy1 = y - y1f, dy2 = y2f - y;
        out[orow + 3 + c] = (dx2 * dy2) * Q11 + (dx1 * dy2) * Q21 +
                            (dx2 * dy1) * Q12 + (dx1 * dy1) * Q22;
    }
}

extern "C" void kernel_launch(void* const* d_in, const int* in_sizes, int n_in,
                              void* d_out, int out_size, void* d_ws, size_t ws_size,
                              hipStream_t stream) {
    const float* inputs = (const float*)d_in[0];  // [B,N,3]; batch 0 = coords
    const float* f1 = (const float*)d_in[1];      // [B,64,56,56]
    const float* f2 = (const float*)d_in[2];      // [B,128,28,28]
    const float* f3 = (const float*)d_in[3];      // [B,256,14,14]
    const float* f4 = (const float*)d_in[4];      // [B,512,7,7]
    float* out = (float*)d_out;

    int B = in_sizes[1] / (64 * 56 * 56);
    int N = in_sizes[0] / (B * 3);

    size_t n1 = (size_t)B * 200704;  // per-level bf16 element counts
    size_t n2 = (size_t)B * 100352;
    size_t n3 = (size_t)B * 50176;
    size_t n4 = (size_t)B * 25088;
    size_t need = (n1 + n2 + n3 + n4) * sizeof(unsigned short);

    dim3 blk(256);
    if (ws_size >= need) {
        unsigned short* o1 = (unsigned short*)d_ws;
        unsigned short* o2 = o1 + n1;
        unsigned short* o3 = o2 + n2;
        unsigned short* o4 = o3 + n3;
        trans_all_k<<<dim3((376320 + 255) / 256, B), blk, 0, stream>>>(
            f1, f2, f3, f4, o1, o2, o3, o4);
        proj_bf16_k<<<dim3(N, B), blk, 0, stream>>>(inputs, o1, o2, o3, o4, out, N);
    } else {
        proj_nchw_k<<<dim3(N, B), blk, 0, stream>>>(inputs, f1, f2, f3, f4, out, N);
    }
}